// Round 17
// baseline (208.770 us; speedup 1.0000x reference)
//
#include <hip/hip_runtime.h>
#include <cstdint>
#include <cstddef>

#define NC 64
#define LN2 0.6931471805599453f

typedef _Float16 halfx4 __attribute__((ext_vector_type(4)));
typedef float floatx4 __attribute__((ext_vector_type(4)));

#define MFMA16(a, b, c) __builtin_amdgcn_mfma_f32_16x16x16f16((a), (b), (c), 0, 0, 0)

template <int CTRL>
static __device__ __forceinline__ float dppf(float x) {
    return __int_as_float(__builtin_amdgcn_update_dpp(
        0, __float_as_int(x), CTRL, 0xf, 0xf, true));
}
static __device__ __forceinline__ float wave_sum_bcast(float x) {
    x = x + dppf<0x111>(x);
    x = x + dppf<0x112>(x);
    x = x + dppf<0x114>(x);
    x = x + dppf<0x118>(x);
    x = x + dppf<0x142>(x);   // row_bcast15
    x = x + dppf<0x143>(x);   // row_bcast31
    return __int_as_float(__builtin_amdgcn_readlane(__float_as_int(x), 63));
}

// ---------- kernel 1: length-rank permutation + gold scores ----------
__global__ __launch_bounds__(64, 1)
void prep_kernel(const float* __restrict__ logits, const float* __restrict__ trans,
                 const float* __restrict__ inita, const int* __restrict__ lens,
                 const int* __restrict__ tags, int* __restrict__ perm,
                 float* __restrict__ gold, int N, int T)
{
    const int b = blockIdx.x;
    const int lane = threadIdx.x;
    const int lb = lens[b];

    int cnt = 0;
    for (int j = lane; j < N; j += 64) {
        int lj = lens[j];
        cnt += (lj < lb || (lj == lb && j < b)) ? 1 : 0;
    }
    float cf = wave_sum_bcast((float)cnt);

    const float* lg = logits + (size_t)b * T * NC;
    const int* tg = tags + (size_t)b * T;
    float g = 0.f;
    for (int t = 1 + lane; t < lb; t += 64) {
        int cur = tg[t], prv = tg[t - 1];
        g += trans[cur * NC + prv] + lg[t * NC + cur];
    }
    g = wave_sum_bcast(g);

    if (lane == 0) {
        int t0 = tg[0];
        gold[b] = inita[t0] + lg[t0] + g;
        perm[(int)(cf + 0.5f)] = b;
    }
}

// ---------- kernel 2: batched MFMA forward/backward CRF ----------
__global__ __launch_bounds__(128, 1)
void crf_mfma(const float* __restrict__ logits, const float* __restrict__ trans,
              const float* __restrict__ inita, const int* __restrict__ lens,
              const int* __restrict__ perm, const float* __restrict__ gold,
              float* __restrict__ out, int N, int T)
{
    const int g = blockIdx.x;          // 32 groups of 16 sequences
    const int tid = threadIdx.x;
    const int wid = tid >> 6;          // wave 0 = forward, wave 1 = backward
    const int lane = tid & 63;
    const int q = lane >> 4;           // class sub-block
    const int col = lane & 15;         // sequence slot within group

    __shared__ float Xf[64][16], Xb[64][16];
    __shared__ float Lshf[16], Lshb[16];

    const int sid = perm[16 * g + col];
    const int mylen = lens[sid];
    const int mym = (mylen - 1) >> 1;
    const float* lgb = logits + (size_t)sid * T * NC;

    // group bounds (uniform per block; computed redundantly per thread)
    int maxm = 0, maxlen = 2, minm = 1 << 30;
    for (int c = 0; c < 16; ++c) {
        int s2 = perm[16 * g + c];
        int ll = lens[s2];
        int mm = (ll - 1) >> 1;
        maxm = mm > maxm ? mm : maxm;
        maxlen = ll > maxlen ? ll : maxlen;
        minm = mm < minm ? mm : minm;
    }

    const floatx4 zf = {0.f, 0.f, 0.f, 0.f};

    // ---- probe A orientation: A = 2^m pattern, B = ones.
    // D=A·B -> D[row]=16*2^row (lane0 reg0 = 16); D=A^T·B -> 65535.
    halfx4 Ao;                              // also reused as the ones-A for colsum
    Ao[0] = (_Float16)1.f; Ao[1] = (_Float16)1.f;
    Ao[2] = (_Float16)1.f; Ao[3] = (_Float16)1.f;
    int flip;
    {
        halfx4 ap;
        float pv = (float)(1 << col);
        ap[0] = (_Float16)pv; ap[1] = (_Float16)pv;
        ap[2] = (_Float16)pv; ap[3] = (_Float16)pv;
        floatx4 dp = MFMA16(ap, Ao, zf);
        flip = __builtin_amdgcn_readfirstlane(dp[0] > 1000.f ? 1 : 0);
    }
    const bool useT = ((wid == 1) ? 1 : 0) ^ flip;

    // ---- resident E fragments (fwd: E; bwd: E^T), orientation-corrected
    halfx4 Afr[4][4];
    #pragma unroll
    for (int mt = 0; mt < 4; ++mt)
        #pragma unroll
        for (int kt = 0; kt < 4; ++kt) {
            halfx4 av;
            #pragma unroll
            for (int i = 0; i < 4; ++i) {
                int m = 16 * mt + col;
                int k = 16 * kt + 4 * q + i;
                float tv = useT ? trans[k * NC + m] : trans[m * NC + k];
                av[i] = (_Float16)__expf(tv);
            }
            Afr[mt][kt] = av;
        }

    // ---- state
    floatx4 U[4];                 // f32 state, class = 16*mt + 4*q + r, seq = col
    halfx4 Bfr[4];                // f16 B-fragments of the state
    floatx4 S0 = zf, S1 = zf, S2 = zf, S3 = zf;   // snapshot
    float Lsnap = 0.f;
    float off = 0.f, s_lag = 1.f, dOff = 0.f;

    auto colsum_update = [&]() {
        halfx4 Bs = Bfr[0] + Bfr[1] + Bfr[2] + Bfr[3];
        floatx4 ds = MFMA16(Ao, Bs, zf);
        float cs = ds[0];
        unsigned bi = __float_as_uint(cs);
        int e = (int)((bi >> 23) & 0xff);
        s_lag = __uint_as_float((unsigned)(254 - e) << 23);   // cs*s in [1,2)
        dOff = (float)(e - 127) * LN2;
    };

    if (wid == 0) {
        // ---------------- forward ----------------
        #pragma unroll
        for (int mt = 0; mt < 4; ++mt) {
            floatx4 ia = reinterpret_cast<const floatx4*>(inita)[4 * mt + q];
            floatx4 l0 = reinterpret_cast<const floatx4*>(lgb)[4 * mt + q];
            #pragma unroll
            for (int r = 0; r < 4; ++r) U[mt][r] = __expf(ia[r] + l0[r]);
        }
        if (mym == 0) { S0 = U[0]; S1 = U[1]; S2 = U[2]; S3 = U[3]; Lsnap = 0.f; }
        #pragma unroll
        for (int kt = 0; kt < 4; ++kt)
            #pragma unroll
            for (int i = 0; i < 4; ++i) Bfr[kt][i] = (_Float16)U[kt][i];
        colsum_update();

        floatx4 RA[4], RB[4];
        {
            const floatx4* r1 = reinterpret_cast<const floatx4*>(lgb + (size_t)1 * NC);
            const floatx4* r2 = reinterpret_cast<const floatx4*>(lgb + (size_t)2 * NC);
            #pragma unroll
            for (int mt = 0; mt < 4; ++mt) { RA[mt] = r1[4 * mt + q]; RB[mt] = r2[4 * mt + q]; }
        }

        auto FSTEP = [&](floatx4* R, int tt) {
            floatx4 F[4];
            #pragma unroll
            for (int mt = 0; mt < 4; ++mt)
                #pragma unroll
                for (int r = 0; r < 4; ++r) F[mt][r] = __expf(R[mt][r]) * s_lag;
            off += dOff;
            int pf = tt + 2; pf = pf < T - 1 ? pf : T - 1;
            const floatx4* rp = reinterpret_cast<const floatx4*>(lgb + (size_t)pf * NC);
            #pragma unroll
            for (int mt = 0; mt < 4; ++mt) R[mt] = rp[4 * mt + q];
            floatx4 D[4];
            #pragma unroll
            for (int mt = 0; mt < 4; ++mt) {
                floatx4 acc = zf;
                acc = MFMA16(Afr[mt][0], Bfr[0], acc);
                acc = MFMA16(Afr[mt][1], Bfr[1], acc);
                acc = MFMA16(Afr[mt][2], Bfr[2], acc);
                acc = MFMA16(Afr[mt][3], Bfr[3], acc);
                D[mt] = acc;
            }
            #pragma unroll
            for (int mt = 0; mt < 4; ++mt)
                #pragma unroll
                for (int r = 0; r < 4; ++r) U[mt][r] = D[mt][r] * F[mt][r];
            if (tt == mym) { S0 = U[0]; S1 = U[1]; S2 = U[2]; S3 = U[3]; Lsnap = off; }
            #pragma unroll
            for (int kt = 0; kt < 4; ++kt)
                #pragma unroll
                for (int i = 0; i < 4; ++i) Bfr[kt][i] = (_Float16)U[kt][i];
            colsum_update();
        };

        int t = 1;
        for (; t + 1 <= maxm; t += 2) { FSTEP(RA, t); FSTEP(RB, t + 1); }
        if (t <= maxm) FSTEP(RA, t);

        #pragma unroll
        for (int mt = 0; mt < 4; ++mt)
            #pragma unroll
            for (int r = 0; r < 4; ++r) {
                float sv = (mt == 0 ? S0[r] : mt == 1 ? S1[r] : mt == 2 ? S2[r] : S3[r]);
                Xf[16 * mt + 4 * q + r][col] = sv;
            }
        if (q == 0) Lshf[col] = Lsnap;
    } else {
        // ---------------- backward ----------------
        #pragma unroll
        for (int mt = 0; mt < 4; ++mt)
            #pragma unroll
            for (int r = 0; r < 4; ++r) U[mt][r] = 1.f;
        s_lag = 1.f; dOff = 0.f; off = 0.f;

        floatx4 RA[4], RB[4];
        {
            int rb = maxlen - 2; rb = rb > 1 ? rb : 1;
            const floatx4* r1 = reinterpret_cast<const floatx4*>(lgb + (size_t)(maxlen - 1) * NC);
            const floatx4* r2 = reinterpret_cast<const floatx4*>(lgb + (size_t)rb * NC);
            #pragma unroll
            for (int mt = 0; mt < 4; ++mt) { RA[mt] = r1[4 * mt + q]; RB[mt] = r2[4 * mt + q]; }
        }

        auto BSTEP = [&](floatx4* R, int tb) {
            if (tb == mylen - 1) {     // activation: start this column's beta chain
                #pragma unroll
                for (int mt = 0; mt < 4; ++mt)
                    #pragma unroll
                    for (int r = 0; r < 4; ++r) U[mt][r] = 1.f;
                off = 0.f; s_lag = 1.f; dOff = 0.f;
            }
            floatx4 W[4];
            #pragma unroll
            for (int mt = 0; mt < 4; ++mt)
                #pragma unroll
                for (int r = 0; r < 4; ++r)
                    W[mt][r] = U[mt][r] * (__expf(R[mt][r]) * s_lag);
            off += dOff;
            int pf = tb - 2; pf = pf > 1 ? pf : 1;
            const floatx4* rp = reinterpret_cast<const floatx4*>(lgb + (size_t)pf * NC);
            #pragma unroll
            for (int mt = 0; mt < 4; ++mt) R[mt] = rp[4 * mt + q];
            #pragma unroll
            for (int kt = 0; kt < 4; ++kt)
                #pragma unroll
                for (int i = 0; i < 4; ++i) Bfr[kt][i] = (_Float16)W[kt][i];
            floatx4 D[4];
            #pragma unroll
            for (int mt = 0; mt < 4; ++mt) {
                floatx4 acc = zf;
                acc = MFMA16(Afr[mt][0], Bfr[0], acc);
                acc = MFMA16(Afr[mt][1], Bfr[1], acc);
                acc = MFMA16(Afr[mt][2], Bfr[2], acc);
                acc = MFMA16(Afr[mt][3], Bfr[3], acc);
                D[mt] = acc;
            }
            colsum_update();           // colsum of W (the consumed B), lagged scale
            #pragma unroll
            for (int mt = 0; mt < 4; ++mt) U[mt] = D[mt];
            if (tb - 1 == mym) { S0 = U[0]; S1 = U[1]; S2 = U[2]; S3 = U[3]; Lsnap = off; }
        };

        int tb = maxlen - 1;
        for (; tb >= minm + 2; tb -= 2) { BSTEP(RA, tb); BSTEP(RB, tb - 1); }
        if (tb == minm + 1) BSTEP(RA, tb);

        #pragma unroll
        for (int mt = 0; mt < 4; ++mt)
            #pragma unroll
            for (int r = 0; r < 4; ++r) {
                float sv = (mt == 0 ? S0[r] : mt == 1 ? S1[r] : mt == 2 ? S2[r] : S3[r]);
                Xb[16 * mt + 4 * q + r][col] = sv;
            }
        if (q == 0) Lshb[col] = Lsnap;
    }

    __syncthreads();

    // ---- combine: logZ = Lf + Lb + log(sum_c Xf[c]*Xb[c]); out = logZ - gold
    if (tid < 16) {
        const int n = tid;
        float acc = 0.f;
        #pragma unroll 8
        for (int c = 0; c < 64; ++c) acc += Xf[c][n] * Xb[c][n];
        int s2 = perm[16 * g + n];
        out[s2] = Lshf[n] + Lshb[n] + __logf(acc) - gold[s2];
    }
}

extern "C" void kernel_launch(void* const* d_in, const int* in_sizes, int n_in,
                              void* d_out, int out_size, void* d_ws, size_t ws_size,
                              hipStream_t stream)
{
    const float* logits = (const float*)d_in[0];   // [N][T][C] f32
    const float* trans  = (const float*)d_in[1];   // [C][C]    f32
    const float* inita  = (const float*)d_in[2];   // [C]       f32
    const int*   lens   = (const int*)d_in[3];     // [N]       i32
    const int*   tags   = (const int*)d_in[4];     // [N][T]    i32
    float*       out    = (float*)d_out;           // [N]       f32

    const int N = 512, T = 1024;
    int*   perm = (int*)d_ws;
    float* gold = (float*)d_ws + 512;

    prep_kernel<<<N, 64, 0, stream>>>(logits, trans, inita, lens, tags, perm, gold, N, T);
    crf_mfma<<<N / 16, 128, 0, stream>>>(logits, trans, inita, lens, perm, gold, out, N, T);
}